// Round 1
// baseline (321.131 us; speedup 1.0000x reference)
//
#include <hip/hip_runtime.h>

typedef unsigned short u16;
typedef short bf16x8 __attribute__((ext_vector_type(8)));
typedef float f32x4 __attribute__((ext_vector_type(4)));

#define MFMA16(a, b, c) __builtin_amdgcn_mfma_f32_16x16x32_bf16((a), (b), (c), 0, 0, 0)

static __device__ __forceinline__ u16 f2bf(float f) {
    union { float f; unsigned int u; } v; v.f = f;
    unsigned int u = v.u;
    u += 0x7fffu + ((u >> 16) & 1u);   // round-to-nearest-even
    return (u16)(u >> 16);
}

// ---------------------------------------------------------------------------
// Prep: starts/counts via binary search (batch_indices sorted) + weights->bf16
// ---------------------------------------------------------------------------
__global__ void prep_kernel(const int* __restrict__ bidx, int N,
                            const float* __restrict__ w_in, const float* __restrict__ w_out,
                            int* __restrict__ starts, int* __restrict__ counts,
                            u16* __restrict__ w_in_bf, u16* __restrict__ w_out_bf) {
    int tid = blockIdx.x * blockDim.x + threadIdx.x;   // grid 256x256 = 65536
    if (tid < 1024) {
        int lo = 0, hi = N;
        while (lo < hi) { int mid = (lo + hi) >> 1; if (bidx[mid] < tid) lo = mid + 1; else hi = mid; }
        int s0 = lo;
        lo = 0; hi = N;
        int v1 = tid + 1;
        while (lo < hi) { int mid = (lo + hi) >> 1; if (bidx[mid] < v1) lo = mid + 1; else hi = mid; }
        starts[tid] = s0;
        counts[tid] = lo - s0;
    }
    if (tid < 49152) {  // 196608 / 4 float4s of in_proj_w
        float4 v = ((const float4*)w_in)[tid];
        ushort4 o; o.x = f2bf(v.x); o.y = f2bf(v.y); o.z = f2bf(v.z); o.w = f2bf(v.w);
        ((ushort4*)w_in_bf)[tid] = o;
    }
    if (tid < 16384) {  // 65536 / 4 float4s of out_proj_w
        float4 v = ((const float4*)w_out)[tid];
        ushort4 o; o.x = f2bf(v.x); o.y = f2bf(v.y); o.z = f2bf(v.z); o.w = f2bf(v.w);
        ((ushort4*)w_out_bf)[tid] = o;
    }
}

// ---------------------------------------------------------------------------
// Fused graph-attention: one workgroup (4 waves) per graph.
// ---------------------------------------------------------------------------
__global__ __launch_bounds__(256, 1) void gat_kernel(
    const float* __restrict__ X, const float* __restrict__ bias_in,
    const float* __restrict__ bias_out,
    const int* __restrict__ starts, const int* __restrict__ counts,
    const u16* __restrict__ w_in_bf, const u16* __restrict__ w_out_bf,
    float* __restrict__ out, float* __restrict__ wout) {

    // LDS: 33792*3 + 36864 + 9216 = 147456 B (gfx950 has 160 KiB/CU -> 1 wg/CU)
    __shared__ u16 x_s[64][264];     // X staging (bf16), later reused for ctx transpose
    __shared__ u16 q_s[64][264];     // q row-major [node][dim]   (+8 pad: 2-way, free)
    __shared__ u16 k_s[64][264];     // k row-major [node][dim]
    __shared__ u16 v_t[256][72];     // v transposed [dim][key]
    __shared__ u16 p_s[4][16][72];   // per-wave P (attn) scratch, C-layout -> A-layout

    const int b = blockIdx.x;
    const int tid = threadIdx.x;
    const int w = tid >> 6;
    const int lane = tid & 63;
    const int n = lane & 15;        // MFMA col / B-row index
    const int quad = lane >> 4;     // MFMA quad
    const int s = starts[b];
    const int c = counts[b];

    // ---- Phase 1: stage X (zero-padded) into LDS as bf16, coalesced float4 ----
    #pragma unroll
    for (int i = 0; i < 16; ++i) {
        int f4 = i * 256 + tid;          // 0..4095 (64 rows x 64 float4)
        int row = f4 >> 6, c4 = f4 & 63;
        float4 v = make_float4(0.f, 0.f, 0.f, 0.f);
        if (row < c) v = ((const float4*)X)[(s + row) * 64 + c4];
        ushort4 o; o.x = f2bf(v.x); o.y = f2bf(v.y); o.z = f2bf(v.z); o.w = f2bf(v.w);
        *(ushort4*)&x_s[row][c4 * 4] = o;
    }
    __syncthreads();

    // ---- Phase 2: QKV = X @ W_in^T + b_in (column-split across waves) ----
    // A-frags: all 64 rows x 256 dims held in regs (32 frags = 128 VGPRs)
    bf16x8 afr[4][8];
    #pragma unroll
    for (int st = 0; st < 4; ++st)
        #pragma unroll
        for (int ks = 0; ks < 8; ++ks)
            afr[st][ks] = *(const bf16x8*)&x_s[st * 16 + n][ks * 32 + quad * 8];

    #pragma unroll 1
    for (int ct = w; ct < 48; ct += 4) {   // 16-col tiles of the 768 QKV outputs
        bf16x8 bfr[8];
        const u16* wr = w_in_bf + (ct * 16 + n) * 256 + quad * 8;
        #pragma unroll
        for (int ks = 0; ks < 8; ++ks) bfr[ks] = *(const bf16x8*)(wr + ks * 32);
        float bias = bias_in[ct * 16 + n];

        f32x4 acc[4];
        #pragma unroll
        for (int st = 0; st < 4; ++st) acc[st] = (f32x4){0.f, 0.f, 0.f, 0.f};
        #pragma unroll
        for (int ks = 0; ks < 8; ++ks)
            #pragma unroll
            for (int st = 0; st < 4; ++st)
                acc[st] = MFMA16(afr[st][ks], bfr[ks], acc[st]);

        #pragma unroll
        for (int st = 0; st < 4; ++st) {
            if (ct < 32) {                           // q or k: row-major store
                u16 (*dst)[264] = (ct < 16) ? q_s : k_s;
                int cc = (ct * 16 + n) & 255;
                #pragma unroll
                for (int r = 0; r < 4; ++r)
                    dst[st * 16 + quad * 4 + r][cc] = f2bf(acc[st][r] + bias);
            } else {                                 // v: transposed store, 4 keys packed
                int vcol = (ct - 32) * 16 + n;
                ushort4 pk;
                pk.x = f2bf(acc[st][0] + bias); pk.y = f2bf(acc[st][1] + bias);
                pk.z = f2bf(acc[st][2] + bias); pk.w = f2bf(acc[st][3] + bias);
                *(ushort4*)&v_t[vcol][st * 16 + quad * 4] = pk;
            }
        }
    }
    __syncthreads();

    // ---- Phase 3: attention. Wave w owns query rows [16w, 16w+16). ----
    const float scale = 0.17677669529663687f;  // 1/sqrt(32)
    const int m0 = w * 16;
    float wacc[4][4];
    #pragma unroll
    for (int t = 0; t < 4; ++t)
        #pragma unroll
        for (int r = 0; r < 4; ++r) wacc[t][r] = 0.f;
    f32x4 ctx[8][2];
    #pragma unroll
    for (int h = 0; h < 8; ++h) { ctx[h][0] = (f32x4){0,0,0,0}; ctx[h][1] = (f32x4){0,0,0,0}; }

    #pragma unroll 1
    for (int h = 0; h < 8; ++h) {
        // scores strip [16 x 64] = q_strip . k^T   (K = HD = 32, single MFMA/tile)
        bf16x8 aq = *(const bf16x8*)&q_s[m0 + n][h * 32 + quad * 8];
        f32x4 sc[4];
        #pragma unroll
        for (int t = 0; t < 4; ++t) {
            bf16x8 bk = *(const bf16x8*)&k_s[t * 16 + n][h * 32 + quad * 8];
            f32x4 z = (f32x4){0.f, 0.f, 0.f, 0.f};
            sc[t] = MFMA16(aq, bk, z);
        }
        // online softmax per row (row = quad*4 + r, cols spread over 16 lanes x 4 tiles)
        float p[4][4], inv[4];
        #pragma unroll
        for (int r = 0; r < 4; ++r) {
            float mx = -1e30f;
            #pragma unroll
            for (int t = 0; t < 4; ++t) {
                float sv = ((t * 16 + n) < c) ? sc[t][r] * scale : -1e30f;
                p[t][r] = sv;
                mx = fmaxf(mx, sv);
            }
            #pragma unroll
            for (int d = 1; d < 16; d <<= 1) mx = fmaxf(mx, __shfl_xor(mx, d, 64));
            float sm = 0.f;
            #pragma unroll
            for (int t = 0; t < 4; ++t) {
                float e = ((t * 16 + n) < c) ? __expf(p[t][r] - mx) : 0.f;
                p[t][r] = e; sm += e;
            }
            #pragma unroll
            for (int d = 1; d < 16; d <<= 1) sm += __shfl_xor(sm, d, 64);
            inv[r] = 1.f / sm;
            #pragma unroll
            for (int t = 0; t < 4; ++t) wacc[t][r] += p[t][r] * (inv[r] * 0.125f);
        }
        // P: C-layout -> LDS (wave-private; in-wave DS ordering, no barrier needed)
        #pragma unroll
        for (int t = 0; t < 4; ++t)
            #pragma unroll
            for (int r = 0; r < 4; ++r)
                p_s[w][quad * 4 + r][t * 16 + n] = f2bf(p[t][r]);
        // ctx_strip[16 x 32] = P . V  (unnormalized; scale rows by inv afterwards)
        #pragma unroll
        for (int nt = 0; nt < 2; ++nt) {
            f32x4 acc = (f32x4){0.f, 0.f, 0.f, 0.f};
            #pragma unroll
            for (int k2 = 0; k2 < 2; ++k2) {
                bf16x8 ap = *(const bf16x8*)&p_s[w][n][k2 * 32 + quad * 8];
                bf16x8 bv = *(const bf16x8*)&v_t[h * 32 + nt * 16 + n][k2 * 32 + quad * 8];
                acc = MFMA16(ap, bv, acc);
            }
            #pragma unroll
            for (int r = 0; r < 4; ++r) ctx[h][nt][r] = acc[r] * inv[r];
        }
    }

    // weights output: head-mean attn [B,64,64]
    #pragma unroll
    for (int t = 0; t < 4; ++t)
        #pragma unroll
        for (int r = 0; r < 4; ++r)
            wout[b * 4096 + (m0 + quad * 4 + r) * 64 + t * 16 + n] = wacc[t][r];

    // ---- Phase 4: out = ctx @ W_out^T + b_out, written [L, B, E] ----
    // ctx C-layout -> A-layout via x_s (free now); wave-private rows, no barrier.
    #pragma unroll
    for (int h = 0; h < 8; ++h)
        #pragma unroll
        for (int nt = 0; nt < 2; ++nt)
            #pragma unroll
            for (int r = 0; r < 4; ++r)
                x_s[m0 + quad * 4 + r][h * 32 + nt * 16 + n] = f2bf(ctx[h][nt][r]);

    bf16x8 actx[8];
    #pragma unroll
    for (int ks = 0; ks < 8; ++ks)
        actx[ks] = *(const bf16x8*)&x_s[m0 + n][ks * 32 + quad * 8];

    #pragma unroll 2
    for (int ct = 0; ct < 16; ++ct) {
        bf16x8 bfr[8];
        const u16* wr = w_out_bf + (ct * 16 + n) * 256 + quad * 8;
        #pragma unroll
        for (int ks = 0; ks < 8; ++ks) bfr[ks] = *(const bf16x8*)(wr + ks * 32);
        f32x4 acc = (f32x4){0.f, 0.f, 0.f, 0.f};
        #pragma unroll
        for (int ks = 0; ks < 8; ++ks) acc = MFMA16(actx[ks], bfr[ks], acc);
        float bias = bias_out[ct * 16 + n];
        #pragma unroll
        for (int r = 0; r < 4; ++r)
            out[(m0 + quad * 4 + r) * 262144 + b * 256 + ct * 16 + n] = acc[r] + bias;
    }
}

// ---------------------------------------------------------------------------
extern "C" void kernel_launch(void* const* d_in, const int* in_sizes, int n_in,
                              void* d_out, int out_size, void* d_ws, size_t ws_size,
                              hipStream_t stream) {
    const float* X     = (const float*)d_in[0];
    const int*   bidx  = (const int*)d_in[1];
    const float* w_in  = (const float*)d_in[2];
    const float* b_in  = (const float*)d_in[3];
    const float* w_out = (const float*)d_in[4];
    const float* b_out = (const float*)d_in[5];
    const int N = in_sizes[1];

    float* out  = (float*)d_out;                 // [64, 1024, 256]
    float* wout = out + 64 * 1024 * 256;         // [1024, 64, 64]

    int* starts   = (int*)d_ws;
    int* counts   = starts + 1024;
    u16* w_in_bf  = (u16*)(counts + 1024);       // 768x256 bf16
    u16* w_out_bf = w_in_bf + 196608;            // 256x256 bf16

    hipLaunchKernelGGL(prep_kernel, dim3(256), dim3(256), 0, stream,
                       bidx, N, w_in, w_out, starts, counts, w_in_bf, w_out_bf);
    hipLaunchKernelGGL(gat_kernel, dim3(1024), dim3(256), 0, stream,
                       X, b_in, b_out, starts, counts, w_in_bf, w_out_bf, out, wout);
}

// Round 4
// 282.866 us; speedup vs baseline: 1.1353x; 1.1353x over previous
//
#include <hip/hip_runtime.h>

typedef unsigned short u16;
typedef short bf16x8 __attribute__((ext_vector_type(8)));
typedef float f32x4 __attribute__((ext_vector_type(4)));

#define MFMA16(a, b, c) __builtin_amdgcn_mfma_f32_16x16x32_bf16((a), (b), (c), 0, 0, 0)

static __device__ __forceinline__ u16 f2bf(float f) {
    union { float f; unsigned int u; } v; v.f = f;
    unsigned int u = v.u;
    u += 0x7fffu + ((u >> 16) & 1u);   // round-to-nearest-even
    return (u16)(u >> 16);
}

// ---------------------------------------------------------------------------
// Prep: starts/counts via binary search (batch_indices sorted) + weights->bf16
// ---------------------------------------------------------------------------
__global__ void prep_kernel(const int* __restrict__ bidx, int N,
                            const float* __restrict__ w_in, const float* __restrict__ w_out,
                            int* __restrict__ starts, int* __restrict__ counts,
                            u16* __restrict__ w_in_bf, u16* __restrict__ w_out_bf) {
    int tid = blockIdx.x * blockDim.x + threadIdx.x;   // grid 192x256 = 49152
    if (tid < 1024) {
        int lo = 0, hi = N;
        while (lo < hi) { int mid = (lo + hi) >> 1; if (bidx[mid] < tid) lo = mid + 1; else hi = mid; }
        int s0 = lo;
        lo = 0; hi = N;
        int v1 = tid + 1;
        while (lo < hi) { int mid = (lo + hi) >> 1; if (bidx[mid] < v1) lo = mid + 1; else hi = mid; }
        starts[tid] = s0;
        counts[tid] = lo - s0;
    }
    {   // 49152 float4s of in_proj_w (768x256)
        float4 v = ((const float4*)w_in)[tid];
        ushort4 o; o.x = f2bf(v.x); o.y = f2bf(v.y); o.z = f2bf(v.z); o.w = f2bf(v.w);
        ((ushort4*)w_in_bf)[tid] = o;
    }
    if (tid < 16384) {  // float4s of out_proj_w (256x256)
        float4 v = ((const float4*)w_out)[tid];
        ushort4 o; o.x = f2bf(v.x); o.y = f2bf(v.y); o.z = f2bf(v.z); o.w = f2bf(v.w);
        ((ushort4*)w_out_bf)[tid] = o;
    }
}

// ---------------------------------------------------------------------------
// Fused graph-attention: one workgroup (4 waves) per graph, head-pair groups.
// LDS 70656 B -> 2 wg/CU (vs 147 KB / 1 wg in round 1).
// ---------------------------------------------------------------------------
__global__ __launch_bounds__(256, 2) void gat_kernel(
    const float* __restrict__ X, const float* __restrict__ bias_in,
    const float* __restrict__ bias_out,
    const int* __restrict__ starts, const int* __restrict__ counts,
    const u16* __restrict__ w_in_bf, const u16* __restrict__ w_out_bf,
    float* __restrict__ out, float* __restrict__ wout) {

    __shared__ u16 qg[64][72];       // q for current head pair [node][dim0..63]
    __shared__ u16 kg[64][72];       // k for current head pair
    __shared__ u16 vt[64][72];       // v transposed [dim0..63][key]
    __shared__ u16 p_s[4][16][72];   // per-wave P scratch (C-layout -> A-layout)
    __shared__ u16 cs[64][264];      // ctx staging (C-layout -> A-layout), persists

    const int b = blockIdx.x;
    const int tid = threadIdx.x;
    const int w = tid >> 6;
    const int lane = tid & 63;
    const int n = lane & 15;        // MFMA col / B-row index
    const int quad = lane >> 4;     // MFMA quad
    const int s = starts[b];
    const int c = counts[b];
    const int m0 = w * 16;

    // ---- Phase 1: X A-fragments straight from global (zero-pad rows >= c) ----
    bf16x8 afr[4][8];
    #pragma unroll
    for (int st = 0; st < 4; ++st) {
        int row = st * 16 + n;
        bool ok = row < c;
        const float* src = X + (long)(s + row) * 256 + quad * 8;
        #pragma unroll
        for (int ks = 0; ks < 8; ++ks) {
            float4 v0 = make_float4(0.f, 0.f, 0.f, 0.f);
            float4 v1 = make_float4(0.f, 0.f, 0.f, 0.f);
            if (ok) {
                v0 = *(const float4*)(src + ks * 32);
                v1 = *(const float4*)(src + ks * 32 + 4);
            }
            bf16x8 a;
            a[0] = (short)f2bf(v0.x); a[1] = (short)f2bf(v0.y);
            a[2] = (short)f2bf(v0.z); a[3] = (short)f2bf(v0.w);
            a[4] = (short)f2bf(v1.x); a[5] = (short)f2bf(v1.y);
            a[6] = (short)f2bf(v1.z); a[7] = (short)f2bf(v1.w);
            afr[st][ks] = a;
        }
    }

    const float scale = 0.17677669529663687f;  // 1/sqrt(32)
    float wacc[4][4];
    #pragma unroll
    for (int t = 0; t < 4; ++t)
        #pragma unroll
        for (int r = 0; r < 4; ++r) wacc[t][r] = 0.f;

    // ---- Phase 2+3: head-pair groups ----
    #pragma unroll 1
    for (int g = 0; g < 4; ++g) {
        // QKV for heads 2g,2g+1: 12 tiles of 16 cols, wave w does j = w, w+4, w+8
        #pragma unroll 1
        for (int i = 0; i < 3; ++i) {
            int j = w + i * 4;          // 0..11
            int type = j >> 2;          // 0=q, 1=k, 2=v
            int sub = j & 3;            // 16-col chunk within the 64-dim pair
            int wrow = type * 256 + g * 64 + sub * 16 + n;
            bf16x8 bfr[8];
            const u16* wr = w_in_bf + wrow * 256 + quad * 8;
            #pragma unroll
            for (int ks = 0; ks < 8; ++ks) bfr[ks] = *(const bf16x8*)(wr + ks * 32);
            float bias = bias_in[wrow];

            f32x4 acc[4];
            #pragma unroll
            for (int st = 0; st < 4; ++st) acc[st] = (f32x4){0.f, 0.f, 0.f, 0.f};
            #pragma unroll
            for (int ks = 0; ks < 8; ++ks)
                #pragma unroll
                for (int st = 0; st < 4; ++st)
                    acc[st] = MFMA16(afr[st][ks], bfr[ks], acc[st]);

            #pragma unroll
            for (int st = 0; st < 4; ++st) {
                if (type == 2) {                       // v: transposed, 4 keys packed
                    ushort4 pk;
                    pk.x = f2bf(acc[st][0] + bias); pk.y = f2bf(acc[st][1] + bias);
                    pk.z = f2bf(acc[st][2] + bias); pk.w = f2bf(acc[st][3] + bias);
                    *(ushort4*)&vt[sub * 16 + n][st * 16 + quad * 4] = pk;
                } else {                               // q/k: row-major
                    u16 (*dst)[72] = type ? kg : qg;
                    #pragma unroll
                    for (int r = 0; r < 4; ++r)
                        dst[st * 16 + quad * 4 + r][sub * 16 + n] = f2bf(acc[st][r] + bias);
                }
            }
        }
        __syncthreads();

        // attention for the 2 heads; wave w owns query rows [16w, 16w+16)
        #pragma unroll 1
        for (int hh = 0; hh < 2; ++hh) {
            int h = g * 2 + hh;
            bf16x8 aq = *(const bf16x8*)&qg[m0 + n][hh * 32 + quad * 8];
            f32x4 sc[4];
            #pragma unroll
            for (int t = 0; t < 4; ++t) {
                bf16x8 bk = *(const bf16x8*)&kg[t * 16 + n][hh * 32 + quad * 8];
                f32x4 z = (f32x4){0.f, 0.f, 0.f, 0.f};
                sc[t] = MFMA16(aq, bk, z);
            }
            float p[4][4], inv[4];
            #pragma unroll
            for (int r = 0; r < 4; ++r) {
                float mx = -1e30f;
                #pragma unroll
                for (int t = 0; t < 4; ++t) {
                    float sv = ((t * 16 + n) < c) ? sc[t][r] * scale : -1e30f;
                    p[t][r] = sv;
                    mx = fmaxf(mx, sv);
                }
                #pragma unroll
                for (int d = 1; d < 16; d <<= 1) mx = fmaxf(mx, __shfl_xor(mx, d, 64));
                float sm = 0.f;
                #pragma unroll
                for (int t = 0; t < 4; ++t) {
                    float e = ((t * 16 + n) < c) ? __expf(p[t][r] - mx) : 0.f;
                    p[t][r] = e; sm += e;
                }
                #pragma unroll
                for (int d = 1; d < 16; d <<= 1) sm += __shfl_xor(sm, d, 64);
                inv[r] = 1.f / sm;
                #pragma unroll
                for (int t = 0; t < 4; ++t) wacc[t][r] += p[t][r] * (inv[r] * 0.125f);
            }
            // P: C-layout -> A-layout via wave-private LDS (in-wave ordering)
            #pragma unroll
            for (int t = 0; t < 4; ++t)
                #pragma unroll
                for (int r = 0; r < 4; ++r)
                    p_s[w][quad * 4 + r][t * 16 + n] = f2bf(p[t][r]);
            // ctx strip = P.V, normalized, straight into transpose staging
            #pragma unroll
            for (int nt = 0; nt < 2; ++nt) {
                f32x4 acc = (f32x4){0.f, 0.f, 0.f, 0.f};
                #pragma unroll
                for (int k2 = 0; k2 < 2; ++k2) {
                    bf16x8 ap = *(const bf16x8*)&p_s[w][n][k2 * 32 + quad * 8];
                    bf16x8 bv = *(const bf16x8*)&vt[hh * 32 + nt * 16 + n][k2 * 32 + quad * 8];
                    acc = MFMA16(ap, bv, acc);
                }
                #pragma unroll
                for (int r = 0; r < 4; ++r)
                    cs[m0 + quad * 4 + r][h * 32 + nt * 16 + n] = f2bf(acc[r] * inv[r]);
            }
        }
        __syncthreads();   // before next group overwrites qg/kg/vt
    }

    // weights output: head-mean attn [B,64,64]
    #pragma unroll
    for (int t = 0; t < 4; ++t)
        #pragma unroll
        for (int r = 0; r < 4; ++r)
            wout[b * 4096 + (m0 + quad * 4 + r) * 64 + t * 16 + n] = wacc[t][r];

    // ---- Phase 4: out = ctx @ W_out^T + b_out, written [L, B, E] ----
    bf16x8 actx[8];
    #pragma unroll
    for (int ks = 0; ks < 8; ++ks)
        actx[ks] = *(const bf16x8*)&cs[m0 + n][ks * 32 + quad * 8];

    #pragma unroll 2
    for (int ct = 0; ct < 16; ++ct) {
        bf16x8 bfr[8];
        const u16* wr = w_out_bf + (ct * 16 + n) * 256 + quad * 8;
        #pragma unroll
        for (int ks = 0; ks < 8; ++ks) bfr[ks] = *(const bf16x8*)(wr + ks * 32);
        f32x4 acc = (f32x4){0.f, 0.f, 0.f, 0.f};
        #pragma unroll
        for (int ks = 0; ks < 8; ++ks) acc = MFMA16(actx[ks], bfr[ks], acc);
        float bias = bias_out[ct * 16 + n];
        #pragma unroll
        for (int r = 0; r < 4; ++r)
            out[(m0 + quad * 4 + r) * 262144 + b * 256 + ct * 16 + n] = acc[r] + bias;
    }
}

// ---------------------------------------------------------------------------
extern "C" void kernel_launch(void* const* d_in, const int* in_sizes, int n_in,
                              void* d_out, int out_size, void* d_ws, size_t ws_size,
                              hipStream_t stream) {
    const float* X     = (const float*)d_in[0];
    const int*   bidx  = (const int*)d_in[1];
    const float* w_in  = (const float*)d_in[2];
    const float* b_in  = (const float*)d_in[3];
    const float* w_out = (const float*)d_in[4];
    const float* b_out = (const float*)d_in[5];
    const int N = in_sizes[1];

    float* out  = (float*)d_out;                 // [64, 1024, 256]
    float* wout = out + 64 * 1024 * 256;         // [1024, 64, 64]

    int* starts   = (int*)d_ws;
    int* counts   = starts + 1024;
    u16* w_in_bf  = (u16*)(counts + 1024);       // 768x256 bf16
    u16* w_out_bf = w_in_bf + 196608;            // 256x256 bf16

    hipLaunchKernelGGL(prep_kernel, dim3(192), dim3(256), 0, stream,
                       bidx, N, w_in, w_out, starts, counts, w_in_bf, w_out_bf);
    hipLaunchKernelGGL(gat_kernel, dim3(1024), dim3(256), 0, stream,
                       X, b_in, b_out, starts, counts, w_in_bf, w_out_bf, out, wout);
}